// Round 3
// baseline (222.883 us; speedup 1.0000x reference)
//
#include <hip/hip_runtime.h>

#define ALPHA     10.0f
#define INV_BETA  20.0f      // 1/0.05
#define FAR_DELTA 1e10f
#define NSAMP     128        // samples per ray (reference N)

// One 64-lane wave per ray; each lane owns samples 2*lane and 2*lane+1.
// Inputs/outputs are float32 (reference dtypes); comparison ref is
// bf16-quantized, threshold ~1.9e-2.
__global__ __launch_bounds__(256) void volsdf_render(
    const float* __restrict__ dist,    // [R,128]
    const float* __restrict__ color,   // [R,128,3]
    const float* __restrict__ depth,   // [R,128]
    float*       __restrict__ out,     // [R*3] color ++ [R*128*3] geometry zeros
    int R)
{
    const int lane = threadIdx.x & 63;
    const int wave = threadIdx.x >> 6;
    const int ray  = blockIdx.x * 4 + wave;   // 4 waves per 256-thread block
    if (ray >= R) return;                     // wave-uniform guard

    const size_t rbase = (size_t)ray * NSAMP;

    // Coalesced float2 loads: 8 B/lane, wave covers the whole ray row.
    float2 di = ((const float2*)(dist  + rbase))[lane];
    float2 dp = ((const float2*)(depth + rbase))[lane];

    // delta[e] = depth[e+1]-depth[e]; last delta = FAR_DELTA.
    float dp_next = __shfl_down(dp.x, 1);
    float delta0  = dp.y - dp.x;
    float delta1  = (lane == 63) ? FAR_DELTA : (dp_next - dp.y);

    // Laplace-CDF density: s=-sdf; s<=0 -> a*0.5*exp(s/b); s>0 -> a*(1-0.5*exp(-s/b))
    float s0 = -di.x, s1 = -di.y;
    float e0 = __expf(-fabsf(s0) * INV_BETA);
    float e1 = __expf(-fabsf(s1) * INV_BETA);
    float dens0 = (s0 <= 0.f) ? (0.5f * ALPHA * e0) : (ALPHA * (1.f - 0.5f * e0));
    float dens1 = (s1 <= 0.f) ? (0.5f * ALPHA * e1) : (ALPHA * (1.f - 0.5f * e1));

    float d0 = dens0 * delta0;
    float d1 = dens1 * delta1;    // lane 63: ~1e11 — must NOT pollute any used prefix

    // Wave-level EXCLUSIVE prefix sum of per-lane pair sums.
    // NOTE: do NOT use (incl - local): lane 63's local ~1e11 catastrophically
    // cancels the ~O(10) base (ulp(1e11)=8192) -> trans=1 at the last samples.
    // Instead shift the inclusive scan up one lane; lane 63's incl is unused.
    float local = d0 + d1;
    float incl  = local;
    #pragma unroll
    for (int off = 1; off < 64; off <<= 1) {
        float v = __shfl_up(incl, off);
        if (lane >= off) incl += v;
    }
    float base = __shfl_up(incl, 1);           // = sum of locals over lanes < lane
    if (lane == 0) base = 0.f;

    float t0 = __expf(-base);
    float t1 = __expf(-(base + d0));
    float w0 = (1.f - __expf(-d0)) * t0;
    float w1 = (1.f - __expf(-d1)) * t1;

    // Colors: 6 contiguous floats per lane (24 B), 8-byte aligned -> 3x dwordx2.
    const float* cp = color + rbase * 3 + (size_t)lane * 6;
    float2 c01 = ((const float2*)cp)[0];       // c0.r, c0.g
    float2 c23 = ((const float2*)cp)[1];       // c0.b, c1.r
    float2 c45 = ((const float2*)cp)[2];       // c1.g, c1.b

    float ar = w0 * c01.x + w1 * c23.y;
    float ag = w0 * c01.y + w1 * c45.x;
    float ab = w0 * c23.x + w1 * c45.y;

    // Wave reduction (64 lanes) of the 3 channel sums.
    #pragma unroll
    for (int off = 32; off > 0; off >>= 1) {
        ar += __shfl_down(ar, off);
        ag += __shfl_down(ag, off);
        ab += __shfl_down(ab, off);
    }
    if (lane == 0) {
        out[(size_t)ray * 3 + 0] = ar;
        out[(size_t)ray * 3 + 1] = ag;
        out[(size_t)ray * 3 + 2] = ab;
    }

    // Geometry output is zeros_like(color); d_out is re-poisoned every call,
    // so write zeros every time. 24 B/lane contiguous per ray.
    float* geo = out + (size_t)R * 3 + rbase * 3 + (size_t)lane * 6;
    float2 z = make_float2(0.f, 0.f);
    ((float2*)geo)[0] = z;
    ((float2*)geo)[1] = z;
    ((float2*)geo)[2] = z;
}

extern "C" void kernel_launch(void* const* d_in, const int* in_sizes, int n_in,
                              void* d_out, int out_size, void* d_ws, size_t ws_size,
                              hipStream_t stream) {
    const float* dist  = (const float*)d_in[0];
    const float* color = (const float*)d_in[1];
    const float* depth = (const float*)d_in[2];
    float* out = (float*)d_out;

    const int R = in_sizes[0] / NSAMP;         // 65536
    const int blocks = (R + 3) / 4;            // 4 rays (waves) per block

    hipLaunchKernelGGL(volsdf_render, dim3(blocks), dim3(256), 0, stream,
                       dist, color, depth, out, R);
}